// Round 2
// baseline (44.814 us; speedup 1.0000x reference)
//
#include <hip/hip_runtime.h>

#define NUF 100000
#define NIF 100000
#define DIM 64
#define LNZ 32
#define NB 16384
#define NI 16384
#define OUTW 66   // D + 2

// 4 rows per wave: 16-lane group per row, each lane owns 4 dims (float4).
// Rows [0, NB) are users, rows [NB, NB+NI) are items.
__global__ __launch_bounds__(256) void ensfm_kernel(
    const float* __restrict__ ue_emb,   // [NUF, 64]
    const float* __restrict__ ie_emb,   // [NIF, 64]
    const float* __restrict__ w_user,   // [NUF]
    const float* __restrict__ w_item,   // [NIF]
    const float* __restrict__ gbias,    // [1]
    const float* __restrict__ h1,       // [64]
    const float* __restrict__ h2,       // [64]
    const int*   __restrict__ u_idx,    // [NB, 32]
    const int*   __restrict__ i_idx,    // [NI, 32]
    float* __restrict__ out)            // P [NB,66] | Q [NI,66] | h2 [64]
{
    const int lane = threadIdx.x & 63;
    const int wib  = threadIdx.x >> 6;          // wave in block (0..3)
    const int g    = lane >> 4;                 // row-group in wave (0..3)
    const int t    = lane & 15;                 // lane in group; owns dims 4t..4t+3
    const int row  = blockIdx.x * 16 + wib * 4 + g;   // 0..32767 exactly

    // h2 passthrough (block 0 only)
    if (blockIdx.x == 0 && threadIdx.x < DIM) {
        out[(size_t)(NB + NI) * OUTW + threadIdx.x] = h2[threadIdx.x];
    }

    const bool is_user = (row < NB);
    const int  r       = is_user ? row : (row - NB);
    const float* emb   = is_user ? ue_emb : ie_emb;
    const float* wtab  = is_user ? w_user : w_item;
    const int*   idxp  = is_user ? u_idx  : i_idx;

    // each lane loads 2 of its row's 32 indices (int2, coalesced)
    const int2 myidx = *reinterpret_cast<const int2*>(idxp + (size_t)r * LNZ + 2 * t);

    // w gather + 16-lane group sum
    float wsum = wtab[myidx.x] + wtab[myidx.y];
    #pragma unroll
    for (int m = 1; m < 16; m <<= 1) wsum += __shfl_xor(wsum, m, 64);

    // gather-accumulate over 32 features; idx for feature l lives in
    // lane (groupbase | l>>1), component l&1
    float4 su = {0.f, 0.f, 0.f, 0.f};
    float4 ss = {0.f, 0.f, 0.f, 0.f};
    const int gbase = lane & 48;
    #pragma unroll 8
    for (int l = 0; l < LNZ; ++l) {
        const int idx = __shfl((l & 1) ? myidx.y : myidx.x, gbase | (l >> 1), 64);
        const float4 e = *reinterpret_cast<const float4*>(emb + (size_t)idx * DIM + 4 * t);
        su.x += e.x; su.y += e.y; su.z += e.z; su.w += e.w;
        ss.x = fmaf(e.x, e.x, ss.x);
        ss.y = fmaf(e.y, e.y, ss.y);
        ss.z = fmaf(e.z, e.z, ss.z);
        ss.w = fmaf(e.w, e.w, ss.w);
    }

    // bi = 0.5*(su^2 - ss); scal = dot(bi, h1) + wsum (+ bias for users)
    const float4 h1v = *reinterpret_cast<const float4*>(h1 + 4 * t);
    float dot = 0.5f * (su.x * su.x - ss.x) * h1v.x
              + 0.5f * (su.y * su.y - ss.y) * h1v.y
              + 0.5f * (su.z * su.z - ss.z) * h1v.z
              + 0.5f * (su.w * su.w - ss.w) * h1v.w;
    #pragma unroll
    for (int m = 1; m < 16; m <<= 1) dot += __shfl_xor(dot, m, 64);

    const float scal = dot + wsum + (is_user ? gbias[0] : 0.0f);

    // write su (64 floats per row) as 2x float2 (rows are 8B-aligned: 66*4=264)
    float* orow = out + (size_t)row * OUTW;
    *reinterpret_cast<float2*>(orow + 4 * t)     = make_float2(su.x, su.y);
    *reinterpret_cast<float2*>(orow + 4 * t + 2) = make_float2(su.z, su.w);
    if (t == 0) {
        if (is_user) { orow[DIM] = scal; orow[DIM + 1] = 1.0f; }
        else         { orow[DIM] = 1.0f; orow[DIM + 1] = scal; }
    }
}

extern "C" void kernel_launch(void* const* d_in, const int* in_sizes, int n_in,
                              void* d_out, int out_size, void* d_ws, size_t ws_size,
                              hipStream_t stream) {
    const float* ue_emb = (const float*)d_in[0];
    const float* ie_emb = (const float*)d_in[1];
    const float* w_user = (const float*)d_in[2];
    const float* w_item = (const float*)d_in[3];
    const float* gbias  = (const float*)d_in[4];
    const float* h1     = (const float*)d_in[5];
    const float* h2     = (const float*)d_in[6];
    const int*   u_idx  = (const int*)d_in[7];
    const int*   i_idx  = (const int*)d_in[8];
    float* out = (float*)d_out;

    const int blocks = (NB + NI) / 16;          // 2048 blocks x 256 threads
    ensfm_kernel<<<blocks, 256, 0, stream>>>(
        ue_emb, ie_emb, w_user, w_item, gbias, h1, h2, u_idx, i_idx, out);
}

// Round 4
// 39.849 us; speedup vs baseline: 1.1246x; 1.1246x over previous
//
#include <hip/hip_runtime.h>

#define NUF 100000
#define NIF 100000
#define DIM 64
#define LNZ 32
#define NB 16384
#define NI 16384
#define OUTW 66   // D + 2

// 4 rows per wave: 16-lane group per row, each lane owns 4 dims (float4).
// XCD-sharded: blocks with (blockIdx&7)<4 process users, others items, so each
// XCD's L2 only sees ONE 25.6 MB embedding table instead of both (51 MB).
__global__ __launch_bounds__(256) void ensfm_kernel(
    const float* __restrict__ ue_emb,   // [NUF, 64]
    const float* __restrict__ ie_emb,   // [NIF, 64]
    const float* __restrict__ w_user,   // [NUF]
    const float* __restrict__ w_item,   // [NIF]
    const float* __restrict__ gbias,    // [1]
    const float* __restrict__ h1,       // [64]
    const float* __restrict__ h2,       // [64]
    const int*   __restrict__ u_idx,    // [NB, 32]
    const int*   __restrict__ i_idx,    // [NI, 32]
    float* __restrict__ out)            // P [NB,66] | Q [NI,66] | h2 [64]
{
    const int lane = threadIdx.x & 63;
    const int wib  = threadIdx.x >> 6;          // wave in block (0..3)
    const int g    = lane >> 4;                 // row-group in wave (0..3)
    const int t    = lane & 15;                 // lane in group; owns dims 4t..4t+3

    // h2 passthrough (block 0 only)
    if (blockIdx.x == 0 && threadIdx.x < DIM) {
        out[(size_t)(NB + NI) * OUTW + threadIdx.x] = h2[threadIdx.x];
    }

    // XCD shard: round-robin dispatch puts block b on XCD b&7.
    const int xcd      = blockIdx.x & 7;
    const bool is_user = (xcd < 4);
    const int sideblk  = (blockIdx.x >> 3) * 4 + (xcd & 3);   // 0..1023
    const int r        = sideblk * 16 + wib * 4 + g;          // 0..16383

    const float* emb  = is_user ? ue_emb : ie_emb;
    const float* wtab = is_user ? w_user : w_item;
    const int*   idxp = is_user ? u_idx  : i_idx;

    // each lane loads 2 of its row's 32 indices (streaming -> nontemporal)
    const int* ibase = idxp + (size_t)r * LNZ + 2 * t;
    int2 myidx;
    myidx.x = __builtin_nontemporal_load(ibase);
    myidx.y = __builtin_nontemporal_load(ibase + 1);

    // w gather + 16-lane group sum
    float wsum = wtab[myidx.x] + wtab[myidx.y];
    #pragma unroll
    for (int m = 1; m < 16; m <<= 1) wsum += __shfl_xor(wsum, m, 64);

    // gather-accumulate over 32 features; idx for feature l lives in
    // lane (groupbase | l>>1), component l&1
    float4 su = {0.f, 0.f, 0.f, 0.f};
    float4 ss = {0.f, 0.f, 0.f, 0.f};
    const int gbase = lane & 48;
    #pragma unroll
    for (int l = 0; l < LNZ; ++l) {
        const int idx = __shfl((l & 1) ? myidx.y : myidx.x, gbase | (l >> 1), 64);
        const float4 e = *reinterpret_cast<const float4*>(emb + (size_t)idx * DIM + 4 * t);
        su.x += e.x; su.y += e.y; su.z += e.z; su.w += e.w;
        ss.x = fmaf(e.x, e.x, ss.x);
        ss.y = fmaf(e.y, e.y, ss.y);
        ss.z = fmaf(e.z, e.z, ss.z);
        ss.w = fmaf(e.w, e.w, ss.w);
    }

    // bi = 0.5*(su^2 - ss); scal = dot(bi, h1) + wsum (+ bias for users)
    const float4 h1v = *reinterpret_cast<const float4*>(h1 + 4 * t);
    float dot = 0.5f * (su.x * su.x - ss.x) * h1v.x
              + 0.5f * (su.y * su.y - ss.y) * h1v.y
              + 0.5f * (su.z * su.z - ss.z) * h1v.z
              + 0.5f * (su.w * su.w - ss.w) * h1v.w;
    #pragma unroll
    for (int m = 1; m < 16; m <<= 1) dot += __shfl_xor(dot, m, 64);

    const float scal = dot + wsum + (is_user ? gbias[0] : 0.0f);

    // output row: users at r, items at NB + r (streaming -> nontemporal)
    const int orow_i = is_user ? r : (NB + r);
    float* orow = out + (size_t)orow_i * OUTW;
    __builtin_nontemporal_store(su.x, orow + 4 * t);
    __builtin_nontemporal_store(su.y, orow + 4 * t + 1);
    __builtin_nontemporal_store(su.z, orow + 4 * t + 2);
    __builtin_nontemporal_store(su.w, orow + 4 * t + 3);
    if (t == 0) {
        if (is_user) {
            __builtin_nontemporal_store(scal, orow + DIM);
            __builtin_nontemporal_store(1.0f, orow + DIM + 1);
        } else {
            __builtin_nontemporal_store(1.0f, orow + DIM);
            __builtin_nontemporal_store(scal, orow + DIM + 1);
        }
    }
}

extern "C" void kernel_launch(void* const* d_in, const int* in_sizes, int n_in,
                              void* d_out, int out_size, void* d_ws, size_t ws_size,
                              hipStream_t stream) {
    const float* ue_emb = (const float*)d_in[0];
    const float* ie_emb = (const float*)d_in[1];
    const float* w_user = (const float*)d_in[2];
    const float* w_item = (const float*)d_in[3];
    const float* gbias  = (const float*)d_in[4];
    const float* h1     = (const float*)d_in[5];
    const float* h2     = (const float*)d_in[6];
    const int*   u_idx  = (const int*)d_in[7];
    const int*   i_idx  = (const int*)d_in[8];
    float* out = (float*)d_out;

    const int blocks = (NB + NI) / 16;          // 2048 blocks x 256 threads
    ensfm_kernel<<<blocks, 256, 0, stream>>>(
        ue_emb, ie_emb, w_user, w_item, gbias, h1, h2, u_idx, i_idx, out);
}